// Round 6
// baseline (171.294 us; speedup 1.0000x reference)
//
#include <hip/hip_runtime.h>
#include <cfloat>
#include <math.h>

#define IMG_B 16
#define IMG_H 1024
#define IMG_W 1280
#define NPIX (IMG_H * IMG_W)          // 1,310,720
#define BINS 256

// k_pre: 32-row slices -> 512 blocks
#define PRE_SLICES 32
#define PRE_NBLK (IMG_B * PRE_SLICES)     // 512
#define PRE_ITERS 40                       // 32*320/256

// k_hist: 16-row slices -> 1024 blocks
#define H_SLICES 64
#define H_NBLK (IMG_B * H_SLICES)          // 1024
#define F4_PER_HSLICE (16 * IMG_W / 4)     // 5120

// ---------- helpers ----------
__device__ __forceinline__ unsigned encf(float f) {
    unsigned u = __float_as_uint(f);
    return (u >> 31) ? ~u : (u | 0x80000000u);
}
__device__ __forceinline__ float decf(unsigned u) {
    unsigned b = (u & 0x80000000u) ? (u & 0x7fffffffu) : ~u;
    return __uint_as_float(b);
}

// ws layout (bytes):
//   mmp   : uint2[512]       @ 0       per-pre-slice (min,max) encoded   4 KB
//   mom   : double[512*4]    @ 4096    per-pre-slice S,S2,LS,LS2        16 KB
//   bhist : uint[1024*256]   @ 20480   per-hist-slice fixed-point hist   1 MB
// All fully overwritten every call -> no init kernel needed.

// ========== Kernel 1: min/max + moments + Laplacian (HBM-bound pass) =======
__global__ __launch_bounds__(256) void k_pre(const float* __restrict__ img,
                                             uint2* __restrict__ mmp,
                                             double* __restrict__ mom) {
    const int blk = blockIdx.x;               // 0..511
    const int tid = threadIdx.x;
    const int b   = blk >> 5;                 // image
    const int sl  = blk & 31;                 // 32-row slice
    const int lane = tid & 63, wv = tid >> 6;

    const float* base = img + (size_t)b * NPIX;
    const int r0 = sl * 32;

    float fs = 0.f, fs2 = 0.f, fls = 0.f, fls2 = 0.f;
    float fmn = FLT_MAX, fmx = -FLT_MAX;

    #pragma unroll 2
    for (int k = 0; k < PRE_ITERS; ++k) {     // 40*256 = 10240 float4
        int i   = tid + k * 256;
        int ri  = i / 320;                    // row within slice
        int c   = i - ri * 320;               // float4 col 0..319
        int r   = r0 + ri;
        const float* rowf = base + (size_t)r * IMG_W;
        float4 m = ((const float4*)rowf)[c];
        float4 up = make_float4(0.f, 0.f, 0.f, 0.f);
        float4 dn = make_float4(0.f, 0.f, 0.f, 0.f);
        if (r > 0)          up = ((const float4*)(rowf - IMG_W))[c];
        if (r < IMG_H - 1)  dn = ((const float4*)(rowf + IMG_W))[c];

        // horizontal neighbors: row boundaries land at lane 0 (320 = 5*64),
        // so cols are consecutive within a wave -> shfl; scalar load only at
        // the wave edge lanes.
        float lft = __shfl_up(m.w, 1u, 64);
        if (lane == 0)  lft = (c > 0)   ? rowf[4 * c - 1] : 0.f;
        float rgt = __shfl_down(m.x, 1u, 64);
        if (lane == 63) rgt = (c < 319) ? rowf[4 * c + 4] : 0.f;

        fs  += (m.x + m.y) + (m.z + m.w);
        fs2 += (m.x * m.x + m.y * m.y) + (m.z * m.z + m.w * m.w);
        fmn = fminf(fmn, fminf(fminf(m.x, m.y), fminf(m.z, m.w)));
        fmx = fmaxf(fmx, fmaxf(fmaxf(m.x, m.y), fmaxf(m.z, m.w)));

        float l0 = up.x + dn.x + lft + m.y - 4.f * m.x;
        float l1 = up.y + dn.y + m.x + m.z - 4.f * m.y;
        float l2 = up.z + dn.z + m.y + m.w - 4.f * m.z;
        float l3 = up.w + dn.w + m.z + rgt - 4.f * m.w;
        fls  += (l0 + l1) + (l2 + l3);
        fls2 += (l0 * l0 + l1 * l1) + (l2 * l2 + l3 * l3);
    }

    for (int o = 32; o; o >>= 1) {
        fs   += __shfl_down(fs,   (unsigned)o, 64);
        fs2  += __shfl_down(fs2,  (unsigned)o, 64);
        fls  += __shfl_down(fls,  (unsigned)o, 64);
        fls2 += __shfl_down(fls2, (unsigned)o, 64);
        fmn = fminf(fmn, __shfl_down(fmn, (unsigned)o, 64));
        fmx = fmaxf(fmx, __shfl_down(fmx, (unsigned)o, 64));
    }
    __shared__ float swred[4][4];
    __shared__ float rmn[4], rmx[4];
    if (lane == 0) {
        swred[0][wv] = fs;  swred[1][wv] = fs2;
        swred[2][wv] = fls; swred[3][wv] = fls2;
        rmn[wv] = fmn; rmx[wv] = fmx;
    }
    __syncthreads();
    if (tid == 0) {
        double S   = (double)swred[0][0] + (double)swred[0][1] + (double)swred[0][2] + (double)swred[0][3];
        double S2  = (double)swred[1][0] + (double)swred[1][1] + (double)swred[1][2] + (double)swred[1][3];
        double LS  = (double)swred[2][0] + (double)swred[2][1] + (double)swred[2][2] + (double)swred[2][3];
        double LS2 = (double)swred[3][0] + (double)swred[3][1] + (double)swred[3][2] + (double)swred[3][3];
        mom[blk * 4 + 0] = S;  mom[blk * 4 + 1] = S2;
        mom[blk * 4 + 2] = LS; mom[blk * 4 + 3] = LS2;
        float mn = fminf(fminf(rmn[0], rmn[1]), fminf(rmn[2], rmn[3]));
        float mx = fmaxf(fmaxf(rmx[0], rmx[1]), fmaxf(rmx[2], rmx[3]));
        mmp[blk] = make_uint2(encf(mn), encf(mx));
    }
}

// ========== Kernel 2: packed-u64 soft histogram, per-wave private ==========
// Per pixel: i0=floor(clamp(p,-0.5,255.5)), w1q=round((p-i0)*2^16);
// A[i0+1] += (1<<32)|w1q.  h[k] = 65536*hi(A[k+1]) - lo(A[k+1]) + lo(A[k]).
__global__ __launch_bounds__(256) void k_hist(const float* __restrict__ img,
                                              const uint2* __restrict__ mmp,
                                              unsigned* __restrict__ bhist) {
    const int blk = blockIdx.x;               // 0..1023
    const int tid = threadIdx.x;
    const int b   = blk >> 6;
    const int wv  = tid >> 6;

    __shared__ unsigned long long lh64[4][BINS + 1];   // per-wave private
    __shared__ float sh_ab[2];

    // image min/max from the 32 pre-slice partials
    if (tid < 32) {
        uint2 e = mmp[b * 32 + tid];
        unsigned emn = e.x, emx = e.y;
        for (int o = 16; o; o >>= 1) {
            emn = min(emn, (unsigned)__shfl_down(emn, (unsigned)o, 64));
            emx = max(emx, (unsigned)__shfl_down(emx, (unsigned)o, 64));
        }
        if (tid == 0) {
            float fmn = decf(emn), fmx = decf(emx);
            float rng = fmx - fmn;
            if (rng == 0.f) rng = 1.f;
            float a = 256.f / rng;             // pp = v*a + bb
            float bb = -fmn * a - 0.5f;
            sh_ab[0] = a; sh_ab[1] = bb;
        }
    }
    for (int i = tid; i < 4 * (BINS + 1); i += 256)
        ((unsigned long long*)lh64)[i] = 0ull;
    __syncthreads();

    const float a = sh_ab[0], bb = sh_ab[1];
    unsigned long long* mylh = lh64[wv];

    const float4* p = (const float4*)img + (size_t)blk * F4_PER_HSLICE;
    #pragma unroll 2
    for (int k = 0; k < 20; ++k) {            // 20*256 = 5120 float4
        float4 v = p[tid + k * 256];
        #pragma unroll
        for (int j = 0; j < 4; ++j) {
            float vv = (j == 0) ? v.x : (j == 1) ? v.y : (j == 2) ? v.z : v.w;
            float pp = fminf(fmaxf(vv * a + bb, -0.5f), 255.5f);
            float fi = floorf(pp);
            int   i0 = (int)fi;               // -1 .. 255
            unsigned w1q = (unsigned)((pp - fi) * 65536.f + 0.5f);
            atomicAdd(&mylh[i0 + 1], 0x100000000ull + (unsigned long long)w1q);
        }
    }
    __syncthreads();

    // merge 4 wave-copies (lo sums < 2^32, hi sums < 2^32 -> no carry mixing)
    unsigned long long a0 = lh64[0][tid]     + lh64[1][tid]     + lh64[2][tid]     + lh64[3][tid];
    unsigned long long a1 = lh64[0][tid + 1] + lh64[1][tid + 1] + lh64[2][tid + 1] + lh64[3][tid + 1];
    unsigned long long h  = ((a1 >> 32) << 16) - (a1 & 0xffffffffull) + (a0 & 0xffffffffull);
    bhist[blk * BINS + tid] = (unsigned)h;    // < 2^31, contention-free
}

// ===================== Kernel 3: reduce + feats + MLP ======================
__global__ __launch_bounds__(256) void k_final(
    const unsigned* __restrict__ bhist, const double* __restrict__ mom,
    const uint2* __restrict__ mmp,
    const float* __restrict__ W1, const float* __restrict__ b1,
    const float* __restrict__ W2, const float* __restrict__ b2,
    const float* __restrict__ W3, const float* __restrict__ b3,
    float* __restrict__ out)
{
    const int ib = blockIdx.x;    // image
    const int tid = threadIdx.x;
    const int lane = tid & 63, wv = tid >> 6;

    __shared__ double dred[4];
    __shared__ float  fred[4];
    __shared__ double smom[4];
    __shared__ unsigned smm2[2];
    __shared__ unsigned sgm[4];
    __shared__ float f5[5], h1[64], h2[64], lg[3];

    // per-bin total over 64 hist-slice histograms (exact in double)
    double h = 0.0;
    for (int s = 0; s < 64; ++s)
        h += (double)bhist[(ib * 64 + s) * BINS + tid];

    double tot = h;
    for (int o = 32; o; o >>= 1) tot += __shfl_down(tot, (unsigned)o, 64);
    if (lane == 0) dred[wv] = tot;
    __syncthreads();
    tot = dred[0] + dred[1] + dred[2] + dred[3];

    double hv = h * (1.0 / 65536.0);
    double tv = tot * (1.0 / 65536.0);
    float hn = (float)(hv / (tv + 1e-10));
    float ce = hn * log2f(hn + 1e-10f);
    for (int o = 32; o; o >>= 1) ce += __shfl_down(ce, (unsigned)o, 64);
    if (lane == 0) fred[wv] = ce;

    if (tid < 32) {   // moments + image min/max over 32 pre-slices
        double q0 = mom[(ib * 32 + tid) * 4 + 0];
        double q1 = mom[(ib * 32 + tid) * 4 + 1];
        double q2 = mom[(ib * 32 + tid) * 4 + 2];
        double q3 = mom[(ib * 32 + tid) * 4 + 3];
        uint2 e = mmp[ib * 32 + tid];
        unsigned emn = e.x, emx = e.y;
        for (int o = 16; o; o >>= 1) {
            q0 += __shfl_down(q0, (unsigned)o, 64);
            q1 += __shfl_down(q1, (unsigned)o, 64);
            q2 += __shfl_down(q2, (unsigned)o, 64);
            q3 += __shfl_down(q3, (unsigned)o, 64);
            emn = min(emn, (unsigned)__shfl_down(emn, (unsigned)o, 64));
            emx = max(emx, (unsigned)__shfl_down(emx, (unsigned)o, 64));
        }
        if (tid == 0) {
            smom[0] = q0; smom[1] = q1; smom[2] = q2; smom[3] = q3;
            smm2[0] = emn; smm2[1] = emx;
        }
    }
    {   // global max over all 512 pre-slice maxima (scale decision)
        unsigned g = max(mmp[tid].y, mmp[256 + tid].y);
        for (int o = 32; o; o >>= 1)
            g = max(g, (unsigned)__shfl_down(g, (unsigned)o, 64));
        if (lane == 0) sgm[wv] = g;
    }
    __syncthreads();

    if (tid == 0) {
        float ent = -(fred[0] + fred[1] + fred[2] + fred[3]) / 8.f;  // /log2(256)
        float gmax = decf(max(max(sgm[0], sgm[1]), max(sgm[2], sgm[3])));
        float sc = (gmax > 1.f) ? (1.f / 16383.f) : 1.f;
        double N = (double)NPIX;
        double S = smom[0], S2 = smom[1], LS = smom[2], LS2 = smom[3];
        double sc2 = (double)sc * (double)sc;
        float var  = (float)((S2  - S  * S  / N) / (N - 1.0) * sc2);
        float lvar = (float)((LS2 - LS * LS / N) / (N - 1.0) * sc2);
        float mn = decf(smm2[0]) * sc;
        float mx = decf(smm2[1]) * sc;
        float* fo = out + 64 + ib * 5;
        fo[0] = var; fo[1] = mn; fo[2] = mx; fo[3] = ent; fo[4] = lvar;
        f5[0] = var; f5[1] = mn; f5[2] = mx; f5[3] = ent; f5[4] = lvar;
    }
    __syncthreads();

    // tiny MLP
    if (tid < 64) {
        float aa = b1[tid];
        #pragma unroll
        for (int k = 0; k < 5; ++k) aa += W1[tid * 5 + k] * f5[k];
        h1[tid] = fmaxf(aa, 0.f);
    }
    __syncthreads();
    if (tid < 64) {
        float a2 = b2[tid];
        #pragma unroll
        for (int k = 0; k < 64; ++k) a2 += W2[tid * 64 + k] * h1[k];
        h2[tid] = fmaxf(a2, 0.f);
    }
    __syncthreads();
    if (tid < 3) {
        float a3 = b3[tid];
        #pragma unroll
        for (int k = 0; k < 64; ++k) a3 += W3[tid * 64 + k] * h2[k];
        lg[tid] = a3;
    }
    __syncthreads();
    if (tid == 0) {
        float m = fmaxf(lg[0], fmaxf(lg[1], lg[2]));
        float e0 = expf(lg[0] - m), e1 = expf(lg[1] - m), e2 = expf(lg[2] - m);
        float inv = 1.f / (e0 + e1 + e2);
        float p0 = e0 * inv, p1 = e1 * inv, p2 = e2 * inv;
        out[16 + ib * 3 + 0] = p0;
        out[16 + ib * 3 + 1] = p1;
        out[16 + ib * 3 + 2] = p2;
        int cid = 0; float bm = p0;
        if (p1 > bm) { bm = p1; cid = 1; }
        if (p2 > bm) { bm = p2; cid = 2; }
        out[ib] = (float)cid;
    }
}

extern "C" void kernel_launch(void* const* d_in, const int* in_sizes, int n_in,
                              void* d_out, int out_size, void* d_ws, size_t ws_size,
                              hipStream_t stream) {
    const float* img = (const float*)d_in[0];
    const float* W1  = (const float*)d_in[1];
    const float* b1  = (const float*)d_in[2];
    const float* W2  = (const float*)d_in[3];
    const float* b2  = (const float*)d_in[4];
    const float* W3  = (const float*)d_in[5];
    const float* b3  = (const float*)d_in[6];
    float* out = (float*)d_out;

    char* ws = (char*)d_ws;
    uint2*    mmp   = (uint2*)ws;                 // 512 uint2      (4 KB)
    double*   mom   = (double*)(ws + 4096);       // 512*4 double   (16 KB)
    unsigned* bhist = (unsigned*)(ws + 20480);    // 1024*256 uint  (1 MB)

    k_pre  <<<PRE_NBLK, 256, 0, stream>>>(img, mmp, mom);
    k_hist <<<H_NBLK,   256, 0, stream>>>(img, mmp, bhist);
    k_final<<<IMG_B,    256, 0, stream>>>(bhist, mom, mmp,
                                          W1, b1, W2, b2, W3, b3, out);
}

// Round 7
// 158.158 us; speedup vs baseline: 1.0831x; 1.0831x over previous
//
#include <hip/hip_runtime.h>
#include <cfloat>
#include <math.h>

#define IMG_B 16
#define IMG_H 1024
#define IMG_W 1280
#define NPIX (IMG_H * IMG_W)          // 1,310,720
#define BINS 256
#define SLICES 64                     // slices per image (16 rows each)
#define NBLK (IMG_B * SLICES)         // 1024
#define F4_PER_SLICE (16 * IMG_W / 4) // 5120

// ---------- helpers ----------
__device__ __forceinline__ unsigned encf(float f) {
    unsigned u = __float_as_uint(f);
    return (u >> 31) ? ~u : (u | 0x80000000u);
}
__device__ __forceinline__ float decf(unsigned u) {
    unsigned b = (u & 0x80000000u) ? (u & 0x7fffffffu) : ~u;
    return __uint_as_float(b);
}

// ws layout (bytes):
//   mmp   : uint2[1024]      @ 0       per-slice (min,max) encoded       8 KB
//   mom   : double[1024*4]   @ 8192    per-slice S,S2,LS,LS2            32 KB
//   bhist : uint[1024*256]   @ 40960   per-slice fixed-point histogram   1 MB
// All fully overwritten every call -> no init kernel needed.

// ========== Kernel 1: min/max + moments + Laplacian (HBM-bound pass) =======
__global__ __launch_bounds__(256) void k_pre(const float* __restrict__ img,
                                             uint2* __restrict__ mmp,
                                             double* __restrict__ mom) {
    const int blk = blockIdx.x;
    const int tid = threadIdx.x;
    const int b   = blk >> 6;           // image
    const int sl  = blk & 63;           // slice (16 rows)
    const int lane = tid & 63, wv = tid >> 6;

    const float* base = img + (size_t)b * NPIX;
    const int r0 = sl * 16;

    float fs = 0.f, fs2 = 0.f, fls = 0.f, fls2 = 0.f;
    float fmn = FLT_MAX, fmx = -FLT_MAX;

    #pragma unroll 2
    for (int k = 0; k < 20; ++k) {               // 20*256 = 5120 float4
        int i   = tid + k * 256;
        int ri  = i / 320;                        // row within slice
        int c   = i - ri * 320;                   // float4 col 0..319
        int r   = r0 + ri;
        const float* rowf = base + (size_t)r * IMG_W;
        float4 m = ((const float4*)rowf)[c];
        float4 up = make_float4(0.f, 0.f, 0.f, 0.f);
        float4 dn = make_float4(0.f, 0.f, 0.f, 0.f);
        if (r > 0)          up = ((const float4*)(rowf - IMG_W))[c];
        if (r < IMG_H - 1)  dn = ((const float4*)(rowf + IMG_W))[c];
        float lft = (c > 0)   ? rowf[4 * c - 1] : 0.f;
        float rgt = (c < 319) ? rowf[4 * c + 4] : 0.f;

        fs  += (m.x + m.y) + (m.z + m.w);
        fs2 += (m.x * m.x + m.y * m.y) + (m.z * m.z + m.w * m.w);
        fmn = fminf(fmn, fminf(fminf(m.x, m.y), fminf(m.z, m.w)));
        fmx = fmaxf(fmx, fmaxf(fmaxf(m.x, m.y), fmaxf(m.z, m.w)));

        float l0 = up.x + dn.x + lft + m.y - 4.f * m.x;
        float l1 = up.y + dn.y + m.x + m.z - 4.f * m.y;
        float l2 = up.z + dn.z + m.y + m.w - 4.f * m.z;
        float l3 = up.w + dn.w + m.z + rgt - 4.f * m.w;
        fls  += (l0 + l1) + (l2 + l3);
        fls2 += (l0 * l0 + l1 * l1) + (l2 * l2 + l3 * l3);
    }

    for (int o = 32; o; o >>= 1) {
        fs   += __shfl_down(fs,   (unsigned)o, 64);
        fs2  += __shfl_down(fs2,  (unsigned)o, 64);
        fls  += __shfl_down(fls,  (unsigned)o, 64);
        fls2 += __shfl_down(fls2, (unsigned)o, 64);
        fmn = fminf(fmn, __shfl_down(fmn, (unsigned)o, 64));
        fmx = fmaxf(fmx, __shfl_down(fmx, (unsigned)o, 64));
    }
    __shared__ float swred[4][4];
    __shared__ float rmn[4], rmx[4];
    if (lane == 0) {
        swred[0][wv] = fs;  swred[1][wv] = fs2;
        swred[2][wv] = fls; swred[3][wv] = fls2;
        rmn[wv] = fmn; rmx[wv] = fmx;
    }
    __syncthreads();
    if (tid == 0) {
        double S   = (double)swred[0][0] + (double)swred[0][1] + (double)swred[0][2] + (double)swred[0][3];
        double S2  = (double)swred[1][0] + (double)swred[1][1] + (double)swred[1][2] + (double)swred[1][3];
        double LS  = (double)swred[2][0] + (double)swred[2][1] + (double)swred[2][2] + (double)swred[2][3];
        double LS2 = (double)swred[3][0] + (double)swred[3][1] + (double)swred[3][2] + (double)swred[3][3];
        mom[blk * 4 + 0] = S;  mom[blk * 4 + 1] = S2;
        mom[blk * 4 + 2] = LS; mom[blk * 4 + 3] = LS2;
        float mn = fminf(fminf(rmn[0], rmn[1]), fminf(rmn[2], rmn[3]));
        float mx = fmaxf(fmaxf(rmx[0], rmx[1]), fmaxf(rmx[2], rmx[3]));
        mmp[blk] = make_uint2(encf(mn), encf(mx));
    }
}

// ========== Kernel 2: packed-u64 soft histogram (1 DS atomic / pixel) ======
// Decomposition: per pixel let i0=floor(clamp(p,-0.5,255.5)), w1q=round((p-i0)*2^16).
// Accumulate A[i0+1] += (1<<32) | w1q.  Then
//   h_fix[k] = 65536*hi(A[k+1]) - lo(A[k+1]) + lo(A[k]),  k in [0,256).
// This equals the two-sided triangular scatter with w0q = 65536 - w1q.
__global__ __launch_bounds__(256) void k_hist(const float* __restrict__ img,
                                              const uint2* __restrict__ mmp,
                                              unsigned* __restrict__ bhist) {
    const int blk = blockIdx.x;
    const int tid = threadIdx.x;
    const int b   = blk >> 6;

    __shared__ unsigned long long lh64[BINS + 1];
    __shared__ float sh_ab[2];

    // image min/max from the 64 slice partials
    if (tid < 64) {
        uint2 e = mmp[b * 64 + tid];
        unsigned emn = e.x, emx = e.y;
        for (int o = 32; o; o >>= 1) {
            emn = min(emn, (unsigned)__shfl_down(emn, (unsigned)o, 64));
            emx = max(emx, (unsigned)__shfl_down(emx, (unsigned)o, 64));
        }
        if (tid == 0) {
            float fmn = decf(emn), fmx = decf(emx);
            float rng = fmx - fmn;
            if (rng == 0.f) rng = 1.f;
            float a = 256.f / rng;                 // pp = v*a + bb
            float bb = -fmn * a - 0.5f;
            sh_ab[0] = a; sh_ab[1] = bb;
        }
    }
    lh64[tid] = 0ull;
    if (tid == 0) lh64[BINS] = 0ull;
    __syncthreads();

    const float a = sh_ab[0], bb = sh_ab[1];

    const float4* p = (const float4*)img + (size_t)blk * F4_PER_SLICE;
    #pragma unroll 2
    for (int k = 0; k < 20; ++k) {               // 20*256 = 5120 float4
        float4 v = p[tid + k * 256];
        #pragma unroll
        for (int j = 0; j < 4; ++j) {
            float vv = (j == 0) ? v.x : (j == 1) ? v.y : (j == 2) ? v.z : v.w;
            float pp = fminf(fmaxf(vv * a + bb, -0.5f), 255.5f);
            float fi = floorf(pp);
            int   i0 = (int)fi;                   // -1 .. 255
            unsigned w1q = (unsigned)((pp - fi) * 65536.f + 0.5f);
            atomicAdd(&lh64[i0 + 1], 0x100000000ull + (unsigned long long)w1q);
        }
    }
    __syncthreads();

    unsigned long long a0 = lh64[tid];
    unsigned long long a1 = lh64[tid + 1];
    unsigned long long h  = ((a1 >> 32) << 16) - (a1 & 0xffffffffull) + (a0 & 0xffffffffull);
    bhist[blk * BINS + tid] = (unsigned)h;       // < 2^31, contention-free
}

// ===================== Kernel 3: reduce + feats + MLP ======================
__global__ __launch_bounds__(256) void k_final(
    const unsigned* __restrict__ bhist, const double* __restrict__ mom,
    const uint2* __restrict__ mmp,
    const float* __restrict__ W1, const float* __restrict__ b1,
    const float* __restrict__ W2, const float* __restrict__ b2,
    const float* __restrict__ W3, const float* __restrict__ b3,
    float* __restrict__ out)
{
    const int ib = blockIdx.x;    // image
    const int tid = threadIdx.x;
    const int lane = tid & 63, wv = tid >> 6;

    __shared__ double dred[4];
    __shared__ float  fred[4];
    __shared__ double smom[4];
    __shared__ unsigned smm2[2];
    __shared__ unsigned sgm[4];
    __shared__ float f5[5], h1[64], h2[64], lg[3];

    // per-bin total over 64 slice histograms (exact in double)
    double h = 0.0;
    for (int s = 0; s < 64; ++s)
        h += (double)bhist[(ib * 64 + s) * BINS + tid];

    double tot = h;
    for (int o = 32; o; o >>= 1) tot += __shfl_down(tot, (unsigned)o, 64);
    if (lane == 0) dred[wv] = tot;
    __syncthreads();
    tot = dred[0] + dred[1] + dred[2] + dred[3];

    double hv = h * (1.0 / 65536.0);
    double tv = tot * (1.0 / 65536.0);
    float hn = (float)(hv / (tv + 1e-10));
    float ce = hn * log2f(hn + 1e-10f);
    for (int o = 32; o; o >>= 1) ce += __shfl_down(ce, (unsigned)o, 64);
    if (lane == 0) fred[wv] = ce;

    if (tid < 64) {   // moments + image min/max
        double q0 = mom[(ib * 64 + tid) * 4 + 0];
        double q1 = mom[(ib * 64 + tid) * 4 + 1];
        double q2 = mom[(ib * 64 + tid) * 4 + 2];
        double q3 = mom[(ib * 64 + tid) * 4 + 3];
        uint2 e = mmp[ib * 64 + tid];
        unsigned emn = e.x, emx = e.y;
        for (int o = 32; o; o >>= 1) {
            q0 += __shfl_down(q0, (unsigned)o, 64);
            q1 += __shfl_down(q1, (unsigned)o, 64);
            q2 += __shfl_down(q2, (unsigned)o, 64);
            q3 += __shfl_down(q3, (unsigned)o, 64);
            emn = min(emn, (unsigned)__shfl_down(emn, (unsigned)o, 64));
            emx = max(emx, (unsigned)__shfl_down(emx, (unsigned)o, 64));
        }
        if (tid == 0) {
            smom[0] = q0; smom[1] = q1; smom[2] = q2; smom[3] = q3;
            smm2[0] = emn; smm2[1] = emx;
        }
    }
    {   // global max over all 1024 slice maxima (scale decision)
        unsigned g = max(max(mmp[tid].y, mmp[256 + tid].y),
                         max(mmp[512 + tid].y, mmp[768 + tid].y));
        for (int o = 32; o; o >>= 1)
            g = max(g, (unsigned)__shfl_down(g, (unsigned)o, 64));
        if (lane == 0) sgm[wv] = g;
    }
    __syncthreads();

    if (tid == 0) {
        float ent = -(fred[0] + fred[1] + fred[2] + fred[3]) / 8.f;  // /log2(256)
        float gmax = decf(max(max(sgm[0], sgm[1]), max(sgm[2], sgm[3])));
        float sc = (gmax > 1.f) ? (1.f / 16383.f) : 1.f;
        double N = (double)NPIX;
        double S = smom[0], S2 = smom[1], LS = smom[2], LS2 = smom[3];
        double sc2 = (double)sc * (double)sc;
        float var  = (float)((S2  - S  * S  / N) / (N - 1.0) * sc2);
        float lvar = (float)((LS2 - LS * LS / N) / (N - 1.0) * sc2);
        float mn = decf(smm2[0]) * sc;
        float mx = decf(smm2[1]) * sc;
        float* fo = out + 64 + ib * 5;
        fo[0] = var; fo[1] = mn; fo[2] = mx; fo[3] = ent; fo[4] = lvar;
        f5[0] = var; f5[1] = mn; f5[2] = mx; f5[3] = ent; f5[4] = lvar;
    }
    __syncthreads();

    // tiny MLP
    if (tid < 64) {
        float aa = b1[tid];
        #pragma unroll
        for (int k = 0; k < 5; ++k) aa += W1[tid * 5 + k] * f5[k];
        h1[tid] = fmaxf(aa, 0.f);
    }
    __syncthreads();
    if (tid < 64) {
        float a2 = b2[tid];
        #pragma unroll
        for (int k = 0; k < 64; ++k) a2 += W2[tid * 64 + k] * h1[k];
        h2[tid] = fmaxf(a2, 0.f);
    }
    __syncthreads();
    if (tid < 3) {
        float a3 = b3[tid];
        #pragma unroll
        for (int k = 0; k < 64; ++k) a3 += W3[tid * 64 + k] * h2[k];
        lg[tid] = a3;
    }
    __syncthreads();
    if (tid == 0) {
        float m = fmaxf(lg[0], fmaxf(lg[1], lg[2]));
        float e0 = expf(lg[0] - m), e1 = expf(lg[1] - m), e2 = expf(lg[2] - m);
        float inv = 1.f / (e0 + e1 + e2);
        float p0 = e0 * inv, p1 = e1 * inv, p2 = e2 * inv;
        out[16 + ib * 3 + 0] = p0;
        out[16 + ib * 3 + 1] = p1;
        out[16 + ib * 3 + 2] = p2;
        int cid = 0; float bm = p0;
        if (p1 > bm) { bm = p1; cid = 1; }
        if (p2 > bm) { bm = p2; cid = 2; }
        out[ib] = (float)cid;
    }
}

extern "C" void kernel_launch(void* const* d_in, const int* in_sizes, int n_in,
                              void* d_out, int out_size, void* d_ws, size_t ws_size,
                              hipStream_t stream) {
    const float* img = (const float*)d_in[0];
    const float* W1  = (const float*)d_in[1];
    const float* b1  = (const float*)d_in[2];
    const float* W2  = (const float*)d_in[3];
    const float* b2  = (const float*)d_in[4];
    const float* W3  = (const float*)d_in[5];
    const float* b3  = (const float*)d_in[6];
    float* out = (float*)d_out;

    char* ws = (char*)d_ws;
    uint2*    mmp   = (uint2*)ws;                 // 1024 uint2     (8 KB)
    double*   mom   = (double*)(ws + 8192);       // 1024*4 double  (32 KB)
    unsigned* bhist = (unsigned*)(ws + 40960);    // 1024*256 uint  (1 MB)

    k_pre  <<<NBLK, 256, 0, stream>>>(img, mmp, mom);
    k_hist <<<NBLK, 256, 0, stream>>>(img, mmp, bhist);
    k_final<<<IMG_B, 256, 0, stream>>>(bhist, mom, mmp,
                                       W1, b1, W2, b2, W3, b3, out);
}